// Round 10
// baseline (3239.964 us; speedup 1.0000x reference)
//
#include <hip/hip_runtime.h>

#define BB 64
#define TT 2048
#define INW 64
#define HH 256
#define NXB 512                  // xprep blocks
#define RPB ((BB * TT) / NXB)    // 256 rows per xprep block
#define BPB 2                    // batches per scan block
#define NBLK (BB / BPB)          // 32 scan blocks
#define NKC 16                   // k-chunks (one per wave)
#define KCW 16                   // k per chunk
#define PSTR 264                 // part[] row stride (floats)

typedef float v2f __attribute__((ext_vector_type(2)));
typedef float v4f __attribute__((ext_vector_type(4)));

__device__ __forceinline__ v4f fma4(v4f a, v4f b, v4f c) {
#if __has_builtin(__builtin_elementwise_fma)
    return __builtin_elementwise_fma(a, b, c);   // -> 2x v_pk_fma_f32
#else
    v4f r;
    r.x = __builtin_fmaf(a.x, b.x, c.x); r.y = __builtin_fmaf(a.y, b.y, c.y);
    r.z = __builtin_fmaf(a.z, b.z, c.z); r.w = __builtin_fmaf(a.w, b.w, c.w);
    return r;
#endif
}
__device__ __forceinline__ v2f fma2(v2f a, v2f b, v2f c) {
#if __has_builtin(__builtin_elementwise_fma)
    return __builtin_elementwise_fma(a, b, c);
#else
    v2f r; r.x = __builtin_fmaf(a.x, b.x, c.x); r.y = __builtin_fmaf(a.y, b.y, c.y); return r;
#endif
}

__device__ __forceinline__ float fast_tanh(float x) {
    // tanh(x) = 1 - 2/(e^{2x}+1); saturates correctly at +/-inf
    float e = __expf(2.0f * x);
    return 1.0f - 2.0f / (e + 1.0f);
}

// LDS-only barrier: skip the vmcnt(0) drain __syncthreads() would add.
__device__ __forceinline__ void lds_barrier() {
    asm volatile("s_waitcnt lgkmcnt(0)" ::: "memory");
    __builtin_amdgcn_s_barrier();
    __builtin_amdgcn_sched_barrier(0);
}

// ---------------------------------------------------------------------------
// Pre-pass: X[row,h] = I[row,:] . W_in[h,:] + b[h]  (no recurrence dependence).
// ---------------------------------------------------------------------------
__global__ __launch_bounds__(256)
void xprep(const float* __restrict__ I,
           const float* __restrict__ W_in,
           const float* __restrict__ bias,
           float* __restrict__ X)
{
    const int h = threadIdx.x;
    const size_t row0 = (size_t)blockIdx.x * RPB;

    v2f w[32];
    {
        const float4* wp = (const float4*)(W_in + (size_t)h * INW);
        #pragma unroll
        for (int i = 0; i < 16; ++i) {
            float4 a = wp[i];
            w[2*i]     = (v2f){a.x, a.y};
            w[2*i + 1] = (v2f){a.z, a.w};
        }
    }
    const float bv = bias[h];

    for (int r = 0; r < RPB; ++r) {
        const float4* ip = (const float4*)(I + (row0 + r) * INW);
        v2f acc0 = {0.f, 0.f}, acc1 = {0.f, 0.f};
        #pragma unroll
        for (int i = 0; i < 16; ++i) {
            float4 iv = ip[i];
            acc0 = fma2(w[2*i],     (v2f){iv.x, iv.y}, acc0);
            acc1 = fma2(w[2*i + 1], (v2f){iv.z, iv.w}, acc1);
        }
        v2f s = acc0 + acc1;
        X[(row0 + r) * HH + h] = s.x + s.y + bv;
    }
}

// ---------------------------------------------------------------------------
// Serial scan, TWO batches per block (32 blocks, 1024 threads = 16 waves).
//
// Across 6 measured structural variants (LDS 64-160 b128/step, VALU 256-384
// cyc/SIMD, 1-2 barriers, 8-16 waves) the per-step time pinned at ~1700 cyc:
// the binding constraint is the serial latency chain of one step (barrier ->
// LDS first-return -> FMA/hadd deps -> part round-trip -> combine+tanh ->
// barrier), not any throughput resource. Fix: co-schedule 2 INDEPENDENT
// recurrences in the same block. Weights are batch-invariant, so each lane
// applies its 64-float W_rec tile (4 rows x 16 k, arch-VGPR resident) to both
// batches' r-vectors: FMA issue per batch-step stays at the 256 cyc/SIMD
// floor while every fixed latency is amortized over 2 batch-steps.
//
// wave w in [0,16): k-chunk [16w, 16w+16); lane l: h-rows [4l, 4l+4).
// Phase 1: 8 uniform v4f r-reads (4/batch) -> 32 v4f-fma -> 2 b128 part
// writes. Phase 2: 512 threads (256 h x 2 batches) combine 16 partials + X,
// update u, store u, write r_buf -- both batches in parallel (v6 idled half
// the block here). Waves 8-9 (idle in phase 2) stage X two steps ahead.
// ---------------------------------------------------------------------------
__global__ __launch_bounds__(1024, 1)
void rnn_scan(const float* __restrict__ x0,
              const float* __restrict__ W_rec,
              float* uX)                      // aliased: X (read) / u_out (write)
{
    __shared__ __align__(16) float r_buf[BPB][HH];
    __shared__ __align__(16) float xbuf[2][BPB][HH];
    __shared__ __align__(16) float part[BPB][NKC][PSTR];

    const int b0   = blockIdx.x * BPB;
    const int tid  = threadIdx.x;
    const int lane = tid & 63;
    const int w    = tid >> 6;          // wave id = k-chunk, 0..15
    const int k0   = w * KCW;
    const int h0   = lane << 2;         // 4 output rows per lane

    const int cb = tid >> 8;            // combine: batch (valid for tid<512)
    const int ch = tid & 255;           // combine: h row
    const int sid = tid - 512;          // stage role: waves 8-9
    const int sb  = (sid >> 6) & 1;     // stage batch
    const int sj  = sid & 63;           // stage float4 index

    // ---- loop-invariant W_rec tile: rows h0..h0+3 x cols [k0, k0+16) ----
    v4f w4[4][4];
    #pragma unroll
    for (int m = 0; m < 4; ++m) {
        const v4f* wp = (const v4f*)(W_rec + (size_t)(h0 + m) * HH + k0);
        #pragma unroll
        for (int i = 0; i < 4; ++i) w4[m][i] = wp[i];
    }

    // ---- state init ----
    float u = 0.0f;
    if (tid < 2 * HH) {
        u = x0[(size_t)(b0 + cb) * HH + ch];
        r_buf[cb][ch] = fast_tanh(u);
    }
    v4f x_next = {0.f, 0.f, 0.f, 0.f};
    if ((unsigned)sid < 128u) {
        ((v4f*)&xbuf[0][sb][0])[sj] = ((const v4f*)(uX + (size_t)(b0 + sb) * TT * HH))[sj];
        x_next = ((const v4f*)(uX + ((size_t)(b0 + sb) * TT + 1) * HH))[sj];
    }
    __syncthreads();

    const v4f* rb0 = (const v4f*)&r_buf[0][k0];
    const v4f* rb1 = (const v4f*)&r_buf[1][k0];

    for (int t = 0; t < TT; ++t) {
        // waves 8-9: issue X[*, t+2] (consumed end of step t+1; ~2 steps cover)
        v4f x_fut = {0.f, 0.f, 0.f, 0.f};
        if ((unsigned)sid < 128u && (t + 2) < TT)
            x_fut = ((const v4f*)(uX + ((size_t)(b0 + sb) * TT + t + 2) * HH))[sj];

        // ---- phase 1: 4 rows x k-chunk w, BOTH batches (shared weights) ----
        v4f a0[4] = {{0,0,0,0},{0,0,0,0},{0,0,0,0},{0,0,0,0}};
        v4f a1[4] = {{0,0,0,0},{0,0,0,0},{0,0,0,0},{0,0,0,0}};
        #pragma unroll
        for (int i = 0; i < 4; ++i) {
            v4f r0 = rb0[i], r1 = rb1[i];        // wave-uniform -> broadcast
            #pragma unroll
            for (int m = 0; m < 4; ++m) {
                a0[m] = fma4(w4[m][i], r0, a0[m]);
                a1[m] = fma4(w4[m][i], r1, a1[m]);
            }
        }
        v4f dv0, dv1;
        dv0.x = (a0[0].x + a0[0].y) + (a0[0].z + a0[0].w);
        dv0.y = (a0[1].x + a0[1].y) + (a0[1].z + a0[1].w);
        dv0.z = (a0[2].x + a0[2].y) + (a0[2].z + a0[2].w);
        dv0.w = (a0[3].x + a0[3].y) + (a0[3].z + a0[3].w);
        dv1.x = (a1[0].x + a1[0].y) + (a1[0].z + a1[0].w);
        dv1.y = (a1[1].x + a1[1].y) + (a1[1].z + a1[1].w);
        dv1.z = (a1[2].x + a1[2].y) + (a1[2].z + a1[2].w);
        dv1.w = (a1[3].x + a1[3].y) + (a1[3].z + a1[3].w);
        *(v4f*)&part[0][w][h0] = dv0;            // consecutive 16B -> conflict-free
        *(v4f*)&part[1][w][h0] = dv1;
        lds_barrier();                           // partials visible; r reads done

        // ---- phase 2: 512 combine units (2 batches x 256 h) in parallel ----
        if (tid < 2 * HH) {
            float p0  = part[cb][ 0][ch], p1  = part[cb][ 1][ch];
            float p2  = part[cb][ 2][ch], p3  = part[cb][ 3][ch];
            float p4  = part[cb][ 4][ch], p5  = part[cb][ 5][ch];
            float p6  = part[cb][ 6][ch], p7  = part[cb][ 7][ch];
            float p8  = part[cb][ 8][ch], p9  = part[cb][ 9][ch];
            float p10 = part[cb][10][ch], p11 = part[cb][11][ch];
            float p12 = part[cb][12][ch], p13 = part[cb][13][ch];
            float p14 = part[cb][14][ch], p15 = part[cb][15][ch];
            float d = ((((p0 + p1) + (p2 + p3)) + ((p4 + p5) + (p6 + p7))) +
                       (((p8 + p9) + (p10 + p11)) + ((p12 + p13) + (p14 + p15))))
                      + xbuf[t & 1][cb][ch];
            u = 0.8f * u + 0.2f * d;
            uX[((size_t)(b0 + cb) * TT + t) * HH + ch] = u;
            r_buf[cb][ch] = fast_tanh(u);
        }
        // waves 8-9 publish X[*, t+1] while combine runs
        if ((unsigned)sid < 128u && (t + 1) < TT) {
            ((v4f*)&xbuf[(t + 1) & 1][sb][0])[sj] = x_next;
            x_next = x_fut;
        }
        lds_barrier();                           // new r / xbuf visible for t+1
    }
}

// y[b,t,o] = sum_h u[b,t,h] * Wout[o,h] + bout[o]. One wave per (b,t) row.
__global__ __launch_bounds__(256)
void readout(const float* __restrict__ u,
             const float* __restrict__ Wout,
             const float* __restrict__ bout,
             float* __restrict__ y)
{
    const int wid  = threadIdx.x >> 6;
    const int lane = threadIdx.x & 63;
    const size_t row = (size_t)blockIdx.x * 4 + wid;   // < BB*TT

    float4 uv = ((const float4*)(u + row * HH))[lane];
    float4 w0 = ((const float4*)Wout)[lane];
    float4 w1 = ((const float4*)(Wout + HH))[lane];

    float acc0 = uv.x * w0.x + uv.y * w0.y + uv.z * w0.z + uv.w * w0.w;
    float acc1 = uv.x * w1.x + uv.y * w1.y + uv.z * w1.z + uv.w * w1.w;

    #pragma unroll
    for (int m = 32; m >= 1; m >>= 1) {
        acc0 += __shfl_xor(acc0, m, 64);
        acc1 += __shfl_xor(acc1, m, 64);
    }
    if (lane == 0) {
        y[row * 2 + 0] = acc0 + bout[0];
        y[row * 2 + 1] = acc1 + bout[1];
    }
}

extern "C" void kernel_launch(void* const* d_in, const int* in_sizes, int n_in,
                              void* d_out, int out_size, void* d_ws, size_t ws_size,
                              hipStream_t stream) {
    const float* x0    = (const float*)d_in[0];
    const float* I     = (const float*)d_in[1];
    const float* W_in  = (const float*)d_in[2];
    const float* W_rec = (const float*)d_in[3];
    const float* bias  = (const float*)d_in[4];
    const float* Wout  = (const float*)d_in[5];
    const float* bout  = (const float*)d_in[6];

    float* u_out = (float*)d_out;                       // also holds X pre-scan
    float* y_out = u_out + (size_t)BB * TT * HH;

    xprep<<<NXB, 256, 0, stream>>>(I, W_in, bias, u_out);
    rnn_scan<<<NBLK, 1024, 0, stream>>>(x0, W_rec, u_out);
    readout<<<(BB * TT) / 4, 256, 0, stream>>>(u_out, Wout, bout, y_out);
}